// Round 17
// baseline (2260.394 us; speedup 1.0000x reference)
//
#include <hip/hip_runtime.h>

#define NN    4096
#define BIGF  1e8f
// Scaled domain: R' = R * K2, K2 = (1/GAMMA)*log2(e).
// softmin'(a,b,c) = m - log2(exp2(m-a)+exp2(m-b)+exp2(m-c)); loss = R'/K2.
#define SQK2f 12.0112245225638540f    // sqrt(K2)
#define BIGK  1.4426950408889634e10f  // 1e8 * K2
#define IK2f  0.00693147180559945309f // 1/K2 = GAMMA*ln2
#define SCH   16       // steps per chunk (r16-validated)
#define NCI   260      // chunks: s = 0..4159
#define OUTS  4158     // lane63 bottom row: j = 4095 at s = 4095 + 63
#define SENTU 0xFFFFFFFFu   // NaN sentinel: DP values are never NaN

#define NB2   32       // fallback config: 32 stripes x 128 rows (R=2)
#define NB1   64       // primary config: 64 stripes x 64 rows (R=1)

// ---------------- fallback: single-block diagonal kernel (verified r1) ----------------
__global__ __launch_bounds__(1024) void dilate_sdtw(const float* __restrict__ pred,
                                                    const float* __restrict__ target,
                                                    float* __restrict__ out) {
    __shared__ float t_s[NN];
    __shared__ float p_s[NN];
    __shared__ float bufA[NN];
    __shared__ float bufB[NN];
    __shared__ float bufC[NN];
    const int tid = threadIdx.x;
    for (int i = tid; i < NN; i += 1024) {
        t_s[i] = target[i]; p_s[i] = pred[i];
        bufA[i] = BIGF; bufB[i] = BIGF; bufC[i] = BIGF;
    }
    __syncthreads();
    float* r2 = bufA; float* r1 = bufB; float* rn = bufC;
    for (int k = 0; k < 2 * NN - 1; ++k) {
        int ilo = k - (NN - 1); if (ilo < 0) ilo = 0;
        int ihi = (k < NN - 1) ? k : (NN - 1);
        for (int i = ilo + tid; i <= ihi; i += 1024) {
            const int j = k - i;
            float diff = t_s[i] - p_s[j];
            float d = diff * diff;
            float a = (i >= 1 && j >= 1) ? r2[i - 1] : ((k == 0) ? 0.0f : BIGF);
            float b = (i >= 1) ? r1[i - 1] : BIGF;
            float c = (j >= 1) ? r1[i] : BIGF;
            float m = fminf(a, fminf(b, c));
            float s = __expf((m - a) * 100.0f) + __expf((m - b) * 100.0f) + __expf((m - c) * 100.0f);
            rn[i] = d + m - 0.01f * __logf(s);
        }
        __syncthreads();
        float* tmp = r2; r2 = r1; r1 = rn; rn = tmp;
    }
    if (tid == 0) out[0] = r1[NN - 1];
}

// ---------------- shared helpers (verified r8-r16) ----------------

__device__ __forceinline__ float softmin3s(float a, float b, float c) {
    float m = fminf(a, fminf(b, c));
    float e = __builtin_amdgcn_exp2f(m - a)
            + __builtin_amdgcn_exp2f(m - b)
            + __builtin_amdgcn_exp2f(m - c);
    return m - __builtin_amdgcn_logf(e);   // logf builtin = log2
}

// lane l <- lane l-1, whole wave, pure VALU:
// row_shr:1 covers lanes 1-15 of each 16-row; row_bcast:15 covers lanes 16/32/48.
__device__ __forceinline__ float nbr1(float v, bool bsel) {
    int iv = __float_as_int(v);
    float a = __int_as_float(__builtin_amdgcn_update_dpp(iv, iv, 0x111, 0xF, 0xF, false)); // row_shr:1
    float b = __int_as_float(__builtin_amdgcn_update_dpp(iv, iv, 0x142, 0xF, 0xF, false)); // row_bcast:15
    return bsel ? b : a;
}

__device__ __forceinline__ void bput(float* p, float v) {
    __hip_atomic_store((unsigned int*)p, __float_as_uint(v),
                       __ATOMIC_RELAXED, __HIP_MEMORY_SCOPE_AGENT);
}
__device__ __forceinline__ unsigned int bgetu(const float* p) {
    return __hip_atomic_load((const unsigned int*)p,
                             __ATOMIC_RELAXED, __HIP_MEMORY_SCOPE_AGENT);
}

__device__ __forceinline__ void uissue(const float* src, float* dst) {
#pragma unroll
    for (int q = 0; q < SCH; ++q) dst[q] = __uint_as_float(bgetu(src + q));
}
__device__ __forceinline__ bool uvalid(const float* dst) {
    bool ok = true;
#pragma unroll
    for (int q = 0; q < SCH; ++q) ok &= (__float_as_uint(dst[q]) != SENTU);
    return ok;
}
__device__ __forceinline__ void upoll(const float* src, float* dst) {
    for (;;) {
        uissue(src, dst);
        if (uvalid(dst)) return;
        __builtin_amdgcn_s_sleep(1);
    }
}

__device__ __forceinline__ void pload(const float* p_s, int base, float* dst) {
#pragma unroll
    for (int q = 0; q < SCH; ++q) {
        int idx = base + q;
        idx = idx < 0 ? 0 : (idx > NN - 1 ? NN - 1 : idx);
        dst[q] = p_s[idx];
    }
}

// ================= R=1 primary: 64 stripes x 64 rows, 1 chained softmin/step =================

template<bool TOP, bool BOT, bool EDGE>
__device__ __forceinline__ void chunkR1(
    int cs, int lane, bool l0, bool bsel, float t,
    float& v, float& u1, float& u2, float upl,
    float4& acc, const float* upc, const float* pc,
    float* __restrict__ bnd_my, float* __restrict__ outp)
{
#pragma unroll
    for (int u = 0; u < SCH; ++u) {
        const int s = cs + u;
        const int j = s - lane;          // off(l) = l, skew 63
        float a, b;
        if (TOP) {
            a = l0 ? ((s == 0) ? 0.0f : BIGK) : u2;
            b = l0 ? BIGK : u1;
        } else {
            float upj  = upc[u];
            float upjm = (u == 0) ? upl : upc[u - 1];
            a = l0 ? upjm : u2;
            b = l0 ? upj  : u1;
        }
        float d = t - pc[u];
        float val = fmaf(d, d, softmin3s(a, b, v));   // row (64*b+lane), col j
        if (EDGE) val = ((unsigned)j < (unsigned)NN) ? val : BIGK;
        if (!BOT) {
            // lane63: j%4 == (u+1)%4; collect 4 cols, publish when j%4==3 (u%4==2)
            switch ((u + 1) & 3) {
                case 0: acc.x = val; break;
                case 1: acc.y = val; break;
                case 2: acc.z = val; break;
                case 3: acc.w = val; break;
            }
            if ((u & 3) == 2) {
                const int base = j - 3;
                if (lane == 63 && (!EDGE || (unsigned)base <= (unsigned)(NN - 4))) {
                    bput(bnd_my + base + 0, acc.x);
                    bput(bnd_my + base + 1, acc.y);
                    bput(bnd_my + base + 2, acc.z);
                    bput(bnd_my + base + 3, acc.w);
                }
            }
        } else if (EDGE) {
            if (lane == 63 && s == OUTS) outp[0] = val * IK2f;
        }
        v = val;
        u2 = u1;
        u1 = nbr1(val, bsel);            // lane l-1's val @ s, consumed at s+1
    }
}

template<bool TOP, bool BOT>
__device__ void stripeR1(int b, int lane, const float* __restrict__ target,
                         const float* p_s, float* bnd, float* outp)
{
    const float t = target[64 * b + lane] * SQK2f;
    float* bnd_my = bnd + (size_t)b * NN;
    const float* bnd_up = bnd + (size_t)(b - 1) * NN;
    const bool l0 = (lane == 0);
    const bool bsel = (lane != 0) && ((lane & 15) == 0);

    float v = BIGK, u1 = BIGK, u2 = BIGK, upl = BIGK;
    float4 acc = {BIGK, BIGK, BIGK, BIGK};
    float upA[SCH], upB[SCH];
    float pcA[SCH], pcB[SCH];

    pload(p_s, -lane, pcA);
    if (!TOP) uissue(bnd_up, upA);

    for (int cp = 0; cp < NCI / 2; ++cp) {
        for (int half = 0; half < 2; ++half) {
            const int ci = 2 * cp + half;
            float* upC = half ? upB : upA;
            float* upN = half ? upA : upB;
            float* pcC = half ? pcB : pcA;
            float* pcN = half ? pcA : pcB;
            const int cs = SCH * ci;
            if (!TOP && cs < NN) {
                if (!uvalid(upC)) upoll(bnd_up + cs, upC);
                if (cs + SCH < NN) uissue(bnd_up + cs + SCH, upN);
            }
            if (ci + 1 < NCI) pload(p_s, cs + SCH - lane, pcN);
            const bool edge = (ci < 4) || (ci >= 256);
            if (edge) chunkR1<TOP, BOT, true >(cs, lane, l0, bsel, t, v, u1, u2, upl, acc, upC, pcC, bnd_my, outp);
            else      chunkR1<TOP, BOT, false>(cs, lane, l0, bsel, t, v, u1, u2, upl, acc, upC, pcC, bnd_my, outp);
            if (!TOP && cs < NN) upl = upC[SCH - 1];
        }
    }
}

__global__ __launch_bounds__(64, 1) void sdtw_r1(const float* __restrict__ pred,
                                                 const float* __restrict__ target,
                                                 float* __restrict__ out,
                                                 float* __restrict__ bnd)
{
    __shared__ float p_s[NN];
    const int lane = threadIdx.x;
    const int bid = blockIdx.x;
    const int b = (bid & 7) * 8 + (bid >> 3);   // group stripe-neighbors per XCD
    for (int i = lane; i < NN; i += 64) p_s[i] = pred[i] * SQK2f;
    __syncthreads();
    if (b == 0)              stripeR1<true , false>(b, lane, target, p_s, bnd, out);
    else if (b == NB1 - 1)   stripeR1<false, true >(b, lane, target, p_s, bnd, out);
    else                     stripeR1<false, false>(b, lane, target, p_s, bnd, out);
}

// ================= R=2 fallback (r16 verbatim, verified 857.6 us) =================

template<bool TOP, bool BOT, bool EDGE>
__device__ __forceinline__ void chunkR2(
    int cs, int lane, bool l0, bool bsel, float t0, float t1,
    float& v0, float& v1, float& u1, float& u2, float upl,
    float4& acc, const float* upc, const float* pc,
    float* __restrict__ bnd_my, float* __restrict__ outp)
{
#pragma unroll
    for (int u = 0; u < SCH; ++u) {
        const int s = cs + u;
        const int j = s - lane;
        float a, b;
        if (TOP) {
            a = l0 ? ((s == 0) ? 0.0f : BIGK) : u2;
            b = l0 ? BIGK : u1;
        } else {
            float upj  = upc[u];
            float upjm = (u == 0) ? upl : upc[u - 1];
            a = l0 ? upjm : u2;
            b = l0 ? upj  : u1;
        }
        float pj = pc[u];
        float d0 = t0 - pj;
        float val0 = fmaf(d0, d0, softmin3s(a, b, v0));
        float d1 = t1 - pj;
        float val1 = fmaf(d1, d1, softmin3s(v0, val0, v1));
        if (EDGE) {
            bool vj = (unsigned)j < (unsigned)NN;
            val0 = vj ? val0 : BIGK;
            val1 = vj ? val1 : BIGK;
        }
        if (!BOT) {
            switch ((u + 1) & 3) {
                case 0: acc.x = val1; break;
                case 1: acc.y = val1; break;
                case 2: acc.z = val1; break;
                case 3: acc.w = val1; break;
            }
            if ((u & 3) == 2) {
                int base = j - 3;
                if (lane == 63 && (!EDGE || (unsigned)base <= (unsigned)(NN - 4))) {
                    bput(bnd_my + base + 0, acc.x);
                    bput(bnd_my + base + 1, acc.y);
                    bput(bnd_my + base + 2, acc.z);
                    bput(bnd_my + base + 3, acc.w);
                }
            }
        } else if (EDGE) {
            if (lane == 63 && s == OUTS) outp[0] = val1 * IK2f;
        }
        v0 = val0; v1 = val1;
        u2 = u1;
        u1 = nbr1(val1, bsel);
    }
}

template<bool TOP, bool BOT>
__device__ void stripeR2(int b, int lane, const float* __restrict__ target,
                         const float* p_s, float* bnd, float* outp)
{
    const float t0 = target[128 * b + 2 * lane]     * SQK2f;
    const float t1 = target[128 * b + 2 * lane + 1] * SQK2f;
    float* bnd_my = bnd + (size_t)b * NN;
    const float* bnd_up = bnd + (size_t)(b - 1) * NN;
    const bool l0 = (lane == 0);
    const bool bsel = (lane != 0) && ((lane & 15) == 0);

    float v0 = BIGK, v1 = BIGK, u1 = BIGK, u2 = BIGK, upl = BIGK;
    float4 acc = {BIGK, BIGK, BIGK, BIGK};
    float upA[SCH], upB[SCH];
    float pcA[SCH], pcB[SCH];

    pload(p_s, -lane, pcA);
    if (!TOP) uissue(bnd_up, upA);

    for (int cp = 0; cp < NCI / 2; ++cp) {
        for (int half = 0; half < 2; ++half) {
            const int ci = 2 * cp + half;
            float* upC = half ? upB : upA;
            float* upN = half ? upA : upB;
            float* pcC = half ? pcB : pcA;
            float* pcN = half ? pcA : pcB;
            const int cs = SCH * ci;
            if (!TOP && cs < NN) {
                if (!uvalid(upC)) upoll(bnd_up + cs, upC);
                if (cs + SCH < NN) uissue(bnd_up + cs + SCH, upN);
            }
            if (ci + 1 < NCI) pload(p_s, cs + SCH - lane, pcN);
            const bool edge = (ci < 4) || (ci >= 256);
            if (edge) chunkR2<TOP, BOT, true >(cs, lane, l0, bsel, t0, t1, v0, v1, u1, u2, upl, acc, upC, pcC, bnd_my, outp);
            else      chunkR2<TOP, BOT, false>(cs, lane, l0, bsel, t0, t1, v0, v1, u1, u2, upl, acc, upC, pcC, bnd_my, outp);
            if (!TOP && cs < NN) upl = upC[SCH - 1];
        }
    }
}

__global__ __launch_bounds__(64, 1) void sdtw_r2(const float* __restrict__ pred,
                                                 const float* __restrict__ target,
                                                 float* __restrict__ out,
                                                 float* __restrict__ bnd)
{
    __shared__ float p_s[NN];
    const int lane = threadIdx.x;
    const int bid = blockIdx.x;
    const int b = (bid & 7) * 4 + (bid >> 3);
    for (int i = lane; i < NN; i += 64) p_s[i] = pred[i] * SQK2f;
    __syncthreads();
    if (b == 0)              stripeR2<true , false>(b, lane, target, p_s, bnd, out);
    else if (b == NB2 - 1)   stripeR2<false, true >(b, lane, target, p_s, bnd, out);
    else                     stripeR2<false, false>(b, lane, target, p_s, bnd, out);
}

extern "C" void kernel_launch(void* const* d_in, const int* in_sizes, int n_in,
                              void* d_out, int out_size, void* d_ws, size_t ws_size,
                              hipStream_t stream) {
    const float* pred   = (const float*)d_in[0];
    const float* target = (const float*)d_in[1];
    float* out = (float*)d_out;

    const size_t need1 = (size_t)(NB1 - 1) * NN * sizeof(float);   // 63 boundary rows
    const size_t need2 = (size_t)NB2 * NN * sizeof(float);
    if (ws_size >= need1) {
        float* bnd = (float*)d_ws;
        hipMemsetAsync(d_ws, 0xFF, need1, stream);
        sdtw_r1<<<dim3(NB1), dim3(64), 0, stream>>>(pred, target, out, bnd);
    } else if (ws_size >= need2) {
        float* bnd = (float*)d_ws;
        hipMemsetAsync(d_ws, 0xFF, need2, stream);
        sdtw_r2<<<dim3(NB2), dim3(64), 0, stream>>>(pred, target, out, bnd);
    } else {
        dilate_sdtw<<<dim3(1), dim3(1024), 0, stream>>>(pred, target, out);
    }
}

// Round 18
// 1139.242 us; speedup vs baseline: 1.9841x; 1.9841x over previous
//
#include <hip/hip_runtime.h>

#define NN    4096
#define BIGF  1e8f
// Scaled domain: R' = R * K2, K2 = (1/GAMMA)*log2(e).
// softmin'(a,b,c) = m - log2(exp2(m-a)+exp2(m-b)+exp2(m-c)); loss = R'/K2.
#define SQK2f 12.0112245225638540f    // sqrt(K2)
#define BIGK  1.4426950408889634e10f  // 1e8 * K2
#define IK2f  0.00693147180559945309f // 1/K2 = GAMMA*ln2
#define NBLK  32       // stripes of 128 rows (64 lanes x 2 rows), C=2 cols/step, stagger-2
#define SCH   16       // steps per chunk => 32 columns per chunk
#define NCI   132      // steps 0..2111
#define OUTS  2110     // lane63: jB = 2*2110 - 126 + 1 = 4095
#define SENTU 0xFFFFFFFFu   // NaN sentinel: DP values are never NaN

// ---------------- fallback: single-block diagonal kernel (verified r1) ----------------
__global__ __launch_bounds__(1024) void dilate_sdtw(const float* __restrict__ pred,
                                                    const float* __restrict__ target,
                                                    float* __restrict__ out) {
    __shared__ float t_s[NN];
    __shared__ float p_s[NN];
    __shared__ float bufA[NN];
    __shared__ float bufB[NN];
    __shared__ float bufC[NN];
    const int tid = threadIdx.x;
    for (int i = tid; i < NN; i += 1024) {
        t_s[i] = target[i]; p_s[i] = pred[i];
        bufA[i] = BIGF; bufB[i] = BIGF; bufC[i] = BIGF;
    }
    __syncthreads();
    float* r2 = bufA; float* r1 = bufB; float* rn = bufC;
    for (int k = 0; k < 2 * NN - 1; ++k) {
        int ilo = k - (NN - 1); if (ilo < 0) ilo = 0;
        int ihi = (k < NN - 1) ? k : (NN - 1);
        for (int i = ilo + tid; i <= ihi; i += 1024) {
            const int j = k - i;
            float diff = t_s[i] - p_s[j];
            float d = diff * diff;
            float a = (i >= 1 && j >= 1) ? r2[i - 1] : ((k == 0) ? 0.0f : BIGF);
            float b = (i >= 1) ? r1[i - 1] : BIGF;
            float c = (j >= 1) ? r1[i] : BIGF;
            float m = fminf(a, fminf(b, c));
            float s = __expf((m - a) * 100.0f) + __expf((m - b) * 100.0f) + __expf((m - c) * 100.0f);
            rn[i] = d + m - 0.01f * __logf(s);
        }
        __syncthreads();
        float* tmp = r2; r2 = r1; r1 = rn; rn = tmp;
    }
    if (tid == 0) out[0] = r1[NN - 1];
}

// ---- C=2 stagger-2: lane l computes 2x2 cells (rows 2l,2l+1 x cols 2s-2l, 2s-2l+1) ----

__device__ __forceinline__ float softmin3s(float a, float b, float c) {
    float m = fminf(a, fminf(b, c));
    float e = __builtin_amdgcn_exp2f(m - a)
            + __builtin_amdgcn_exp2f(m - b)
            + __builtin_amdgcn_exp2f(m - c);
    return m - __builtin_amdgcn_logf(e);   // logf builtin = log2
}

// lane l <- lane l-1, whole wave, pure VALU (verified r8/r9)
__device__ __forceinline__ float nbr1(float v, bool bsel) {
    int iv = __float_as_int(v);
    float a = __int_as_float(__builtin_amdgcn_update_dpp(iv, iv, 0x111, 0xF, 0xF, false)); // row_shr:1
    float b = __int_as_float(__builtin_amdgcn_update_dpp(iv, iv, 0x142, 0xF, 0xF, false)); // row_bcast:15
    return bsel ? b : a;
}

__device__ __forceinline__ void bput(float* p, float v) {
    __hip_atomic_store((unsigned int*)p, __float_as_uint(v),
                       __ATOMIC_RELAXED, __HIP_MEMORY_SCOPE_AGENT);
}
__device__ __forceinline__ unsigned int bgetu(const float* p) {
    return __hip_atomic_load((const unsigned int*)p,
                             __ATOMIC_RELAXED, __HIP_MEMORY_SCOPE_AGENT);
}

// boundary chunk = 32 columns; issue-early / validate-late (verified r9-r16)
__device__ __forceinline__ void uissue(const float* src, float* dst) {
#pragma unroll
    for (int q = 0; q < 32; ++q) dst[q] = __uint_as_float(bgetu(src + q));
}
__device__ __forceinline__ bool uvalid(const float* dst) {
    bool ok = true;
#pragma unroll
    for (int q = 0; q < 32; ++q) ok &= (__float_as_uint(dst[q]) != SENTU);
    return ok;
}
__device__ __forceinline__ void upoll(const float* src, float* dst) {
    for (;;) {
        uissue(src, dst);
        if (uvalid(dst)) return;
        __builtin_amdgcn_s_sleep(1);
    }
}

// p for one chunk: 32 consecutive cols from even base (clamped), 16x float2 (r5-verified clean)
__device__ __forceinline__ void pload(const float* p_s, int base, float2* dst) {
#pragma unroll
    for (int q = 0; q < 16; ++q) {
        int idx = base + 2 * q;
        idx = idx < 0 ? 0 : (idx > NN - 2 ? NN - 2 : idx);
        dst[q] = *(const float2*)(p_s + idx);
    }
}

template<bool TOP, bool BOT, bool EDGE>
__device__ __forceinline__ void chunkC2(
    int ci, int lane, bool l0, bool bsel, float t0, float t1,
    float& v0b, float& v1b, float& u1a, float& u1b, float& u2b, float upl,
    float2& acc, const float* upc, const float2* pc,
    float* __restrict__ bnd_my, float* __restrict__ outp)
{
#pragma unroll
    for (int u = 0; u < SCH; ++u) {
        const int s  = SCH * ci + u;
        const int jA = 2 * s - 2 * lane;          // first col of the 2x2 block
        // up-row (lane l-1's row1) values: cols jA-1 (s-2), jA (s-1), jA+1 (s-1)
        float aA, bA, bB;
        if (TOP) {
            aA = l0 ? ((s == 0) ? 0.0f : BIGK) : u2b;
            bA = l0 ? BIGK : u1a;
            bB = l0 ? BIGK : u1b;
        } else {
            float upjm = (u == 0) ? upl : upc[2 * u - 1];
            aA = l0 ? upjm         : u2b;
            bA = l0 ? upc[2 * u]     : u1a;
            bB = l0 ? upc[2 * u + 1] : u1b;
        }
        float2 pj = pc[u];
        // row0 col jA: a=up[jA-1], b=up[jA], c=own row0 jA-1 (prev val0b)
        float dA0 = t0 - pj.x;
        float val0a = fmaf(dA0, dA0, softmin3s(aA, bA, v0b));
        // row0 col jB: a=up[jA], b=up[jB], c=val0a
        float dB0 = t0 - pj.y;
        float val0b = fmaf(dB0, dB0, softmin3s(bA, bB, val0a));
        // row1 col jA: a=prev val0b, b=val0a, c=prev val1b
        float dA1 = t1 - pj.x;
        float val1a = fmaf(dA1, dA1, softmin3s(v0b, val0a, v1b));
        // row1 col jB: a=val0a, b=val0b, c=val1a
        float dB1 = t1 - pj.y;
        float val1b_ = fmaf(dB1, dB1, softmin3s(val0a, val0b, val1a));
        if (EDGE) {
            bool vA = (unsigned)jA < (unsigned)NN;
            bool vB = (unsigned)(jA + 1) < (unsigned)NN;
            val0a = vA ? val0a : BIGK;  val1a  = vA ? val1a  : BIGK;
            val0b = vB ? val0b : BIGK;  val1b_ = vB ? val1b_ : BIGK;
        }
        if (!BOT) {
            if (EDGE) {
                // per-column publishes with individual guards (partial groups at borders)
                if (lane == 63) {
                    if ((unsigned)jA < (unsigned)NN)       bput(bnd_my + jA,     val1a);
                    if ((unsigned)(jA + 1) < (unsigned)NN) bput(bnd_my + jA + 1, val1b_);
                }
            } else {
                if (u & 1) {
                    if (lane == 63) {
                        const int base = jA - 2;       // cols jA-2..jA+1, all in range (non-EDGE)
                        bput(bnd_my + base + 0, acc.x);
                        bput(bnd_my + base + 1, acc.y);
                        bput(bnd_my + base + 2, val1a);
                        bput(bnd_my + base + 3, val1b_);
                    }
                } else {
                    acc.x = val1a; acc.y = val1b_;
                }
            }
        } else if (EDGE) {
            if (lane == 63 && s == OUTS) outp[0] = val1b_ * IK2f;
        }
        // rotate delay line (order matters)
        u2b = u1b;
        u1a = nbr1(val1a,  bsel);
        u1b = nbr1(val1b_, bsel);
        v0b = val0b; v1b = val1b_;
    }
}

template<bool TOP, bool BOT>
__device__ __forceinline__ void chunk_iter(
    int ci, int lane, bool l0, bool bsel, float t0, float t1,
    float& v0b, float& v1b, float& u1a, float& u1b, float& u2b, float& upl,
    float2& acc,
    float* upC, float* upN, float2* pcC, float2* pcN,
    const float* p_s, const float* __restrict__ bnd_up, float* __restrict__ bnd_my,
    float* __restrict__ outp)
{
    const int cs = 32 * ci;                        // first column of this chunk
    if (!TOP && cs < NN) {
        if (!uvalid(upC)) upoll(bnd_up + cs, upC);        // fast path: issued last chunk
        if (cs + 32 < NN) uissue(bnd_up + cs + 32, upN);  // issue next chunk, no wait
    }
    if (ci + 1 < NCI) pload(p_s, cs + 32 - 2 * lane, pcN);

    const bool edge = (ci < 4) || (ci >= 128);
    if (edge) chunkC2<TOP, BOT, true >(ci, lane, l0, bsel, t0, t1, v0b, v1b,
                                       u1a, u1b, u2b, upl, acc, upC, pcC, bnd_my, outp);
    else      chunkC2<TOP, BOT, false>(ci, lane, l0, bsel, t0, t1, v0b, v1b,
                                       u1a, u1b, u2b, upl, acc, upC, pcC, bnd_my, outp);
    if (!TOP && cs < NN) upl = upC[31];
}

template<bool TOP, bool BOT>
__device__ void stripe(int b, int lane, const float* __restrict__ target,
                       const float* p_s, float* bnd, float* outp)
{
    const float t0 = target[128 * b + 2 * lane]     * SQK2f;
    const float t1 = target[128 * b + 2 * lane + 1] * SQK2f;
    float* bnd_my = bnd + (size_t)b * NN;
    const float* bnd_up = bnd + (size_t)(b - 1) * NN;
    const bool l0 = (lane == 0);
    const bool bsel = (lane != 0) && ((lane & 15) == 0);   // lanes 16/32/48: row-crossing

    float v0b = BIGK, v1b = BIGK, u1a = BIGK, u1b = BIGK, u2b = BIGK, upl = BIGK;
    float2 acc = {BIGK, BIGK};
    float upA[32], upB[32];
    float2 pcA[16], pcB[16];

    pload(p_s, -2 * lane, pcA);
    if (!TOP) uissue(bnd_up, upA);   // prologue issue for chunk 0

    for (int cp = 0; cp < NCI / 2; ++cp) {
        chunk_iter<TOP, BOT>(2 * cp,     lane, l0, bsel, t0, t1, v0b, v1b,
                             u1a, u1b, u2b, upl, acc,
                             upA, upB, pcA, pcB, p_s, bnd_up, bnd_my, outp);
        chunk_iter<TOP, BOT>(2 * cp + 1, lane, l0, bsel, t0, t1, v0b, v1b,
                             u1a, u1b, u2b, upl, acc,
                             upB, upA, pcB, pcA, p_s, bnd_up, bnd_my, outp);
    }
}

__global__ __launch_bounds__(64, 1) void sdtw_c2(const float* __restrict__ pred,
                                                 const float* __restrict__ target,
                                                 float* __restrict__ out,
                                                 float* __restrict__ bnd)
{
    __shared__ float p_s[NN];
    const int lane = threadIdx.x;
    const int bid = blockIdx.x;
    const int b = (bid & 7) * 4 + (bid >> 3);   // group stripe-neighbors per XCD
    for (int i = lane; i < NN; i += 64) p_s[i] = pred[i] * SQK2f;
    __syncthreads();
    if (b == 0)                stripe<true , false>(b, lane, target, p_s, bnd, out);
    else if (b == NBLK - 1)    stripe<false, true >(b, lane, target, p_s, bnd, out);
    else                       stripe<false, false>(b, lane, target, p_s, bnd, out);
}

extern "C" void kernel_launch(void* const* d_in, const int* in_sizes, int n_in,
                              void* d_out, int out_size, void* d_ws, size_t ws_size,
                              hipStream_t stream) {
    const float* pred   = (const float*)d_in[0];
    const float* target = (const float*)d_in[1];
    float* out = (float*)d_out;

    const size_t need = (size_t)NBLK * NN * sizeof(float);
    if (ws_size >= need) {
        float* bnd = (float*)d_ws;
        hipMemsetAsync(d_ws, 0xFF, need, stream);   // NaN-sentinel fill (value-carried readiness)
        sdtw_c2<<<dim3(NBLK), dim3(64), 0, stream>>>(pred, target, out, bnd);
    } else {
        dilate_sdtw<<<dim3(1), dim3(1024), 0, stream>>>(pred, target, out);
    }
}

// Round 19
// 991.156 us; speedup vs baseline: 2.2806x; 1.1494x over previous
//
#include <hip/hip_runtime.h>

#define NN    4096
#define BIGF  1e8f
// Scaled domain: R' = R * K2, K2 = (1/GAMMA)*log2(e).
// softmin'(a,b,c) = m - log2(exp2(m-a)+exp2(m-b)+exp2(m-c)); loss = R'/K2.
#define SQK2f 12.0112245225638540f    // sqrt(K2)
#define BIGK  1.4426950408889634e10f  // 1e8 * K2
#define IK2f  0.00693147180559945309f // 1/K2 = GAMMA*ln2
#define NBLK  32       // stripes of 128 rows (64 lanes x R=2), skew 63 (r9/r16 mapping)
#define SCH   16       // steps per chunk (r16-validated)
#define NCI   260      // chunks: s = 0..4159
#define OUTS  4158     // lane63: j = 4095 at s = 4095 + 63
#define SENTU 0xFFFFFFFFu   // NaN sentinel: DP values are never NaN

// ---------------- fallback: single-block diagonal kernel (verified r1) ----------------
__global__ __launch_bounds__(1024) void dilate_sdtw(const float* __restrict__ pred,
                                                    const float* __restrict__ target,
                                                    float* __restrict__ out) {
    __shared__ float t_s[NN];
    __shared__ float p_s[NN];
    __shared__ float bufA[NN];
    __shared__ float bufB[NN];
    __shared__ float bufC[NN];
    const int tid = threadIdx.x;
    for (int i = tid; i < NN; i += 1024) {
        t_s[i] = target[i]; p_s[i] = pred[i];
        bufA[i] = BIGF; bufB[i] = BIGF; bufC[i] = BIGF;
    }
    __syncthreads();
    float* r2 = bufA; float* r1 = bufB; float* rn = bufC;
    for (int k = 0; k < 2 * NN - 1; ++k) {
        int ilo = k - (NN - 1); if (ilo < 0) ilo = 0;
        int ihi = (k < NN - 1) ? k : (NN - 1);
        for (int i = ilo + tid; i <= ihi; i += 1024) {
            const int j = k - i;
            float diff = t_s[i] - p_s[j];
            float d = diff * diff;
            float a = (i >= 1 && j >= 1) ? r2[i - 1] : ((k == 0) ? 0.0f : BIGF);
            float b = (i >= 1) ? r1[i - 1] : BIGF;
            float c = (j >= 1) ? r1[i] : BIGF;
            float m = fminf(a, fminf(b, c));
            float s = __expf((m - a) * 100.0f) + __expf((m - b) * 100.0f) + __expf((m - c) * 100.0f);
            rn[i] = d + m - 0.01f * __logf(s);
        }
        __syncthreads();
        float* tmp = r2; r2 = r1; r1 = rn; rn = tmp;
    }
    if (tid == 0) out[0] = r1[NN - 1];
}

// ---- r16 core verbatim + fine-grained (4-col) polling for chunk 0 (fill-lag trim) ----

__device__ __forceinline__ float softmin3s(float a, float b, float c) {
    float m = fminf(a, fminf(b, c));
    float e = __builtin_amdgcn_exp2f(m - a)
            + __builtin_amdgcn_exp2f(m - b)
            + __builtin_amdgcn_exp2f(m - c);
    return m - __builtin_amdgcn_logf(e);   // logf builtin = log2
}

// lane l <- lane l-1, whole wave, pure VALU (verified r8-r16)
__device__ __forceinline__ float nbr1(float v, bool bsel) {
    int iv = __float_as_int(v);
    float a = __int_as_float(__builtin_amdgcn_update_dpp(iv, iv, 0x111, 0xF, 0xF, false)); // row_shr:1
    float b = __int_as_float(__builtin_amdgcn_update_dpp(iv, iv, 0x142, 0xF, 0xF, false)); // row_bcast:15
    return bsel ? b : a;
}

__device__ __forceinline__ void bput(float* p, float v) {
    __hip_atomic_store((unsigned int*)p, __float_as_uint(v),
                       __ATOMIC_RELAXED, __HIP_MEMORY_SCOPE_AGENT);
}
__device__ __forceinline__ unsigned int bgetu(const float* p) {
    return __hip_atomic_load((const unsigned int*)p,
                             __ATOMIC_RELAXED, __HIP_MEMORY_SCOPE_AGENT);
}

__device__ __forceinline__ void uissue(const float* src, float* dst) {
#pragma unroll
    for (int q = 0; q < SCH; ++q) dst[q] = __uint_as_float(bgetu(src + q));
}
__device__ __forceinline__ bool uvalid(const float* dst) {
    bool ok = true;
#pragma unroll
    for (int q = 0; q < SCH; ++q) ok &= (__float_as_uint(dst[q]) != SENTU);
    return ok;
}
__device__ __forceinline__ void upoll(const float* src, float* dst) {
    for (;;) {
        uissue(src, dst);
        if (uvalid(dst)) return;
        __builtin_amdgcn_s_sleep(1);
    }
}
// 4-column blocking poll, matching the producer's 4-col publish groups
__device__ __forceinline__ void upoll4(const float* src, float* dst) {
    for (;;) {
        bool ok = true;
#pragma unroll
        for (int q = 0; q < 4; ++q) {
            unsigned int x = bgetu(src + q);
            dst[q] = __uint_as_float(x);
            ok &= (x != SENTU);
        }
        if (ok) return;
        __builtin_amdgcn_s_sleep(1);
    }
}

__device__ __forceinline__ void pload(const float* p_s, int base, float* dst) {
#pragma unroll
    for (int q = 0; q < SCH; ++q) {
        int idx = base + q;
        idx = idx < 0 ? 0 : (idx > NN - 1 ? NN - 1 : idx);
        dst[q] = p_s[idx];
    }
}

template<bool TOP, bool BOT, bool EDGE, bool FINE>
__device__ __forceinline__ void chunk16(
    int cs, int lane, bool l0, bool bsel, float t0, float t1,
    float& v0, float& v1, float& u1, float& u2, float upl,
    float4& acc, float* upc, const float* pc, const float* fine_src,
    float* __restrict__ bnd_my, float* __restrict__ outp)
{
#pragma unroll
    for (int u = 0; u < SCH; ++u) {
        if (FINE && (u & 3) == 0) upoll4(fine_src + u, upc + u);   // consume as published
        const int s = cs + u;
        const int j = s - lane;          // off(l) = l, skew 63
        float a, b;
        if (TOP) {
            a = l0 ? ((s == 0) ? 0.0f : BIGK) : u2;
            b = l0 ? BIGK : u1;
        } else {
            float upj  = upc[u];
            float upjm = (u == 0) ? upl : upc[u - 1];
            a = l0 ? upjm : u2;
            b = l0 ? upj  : u1;
        }
        float pj = pc[u];
        float d0 = t0 - pj;
        float val0 = fmaf(d0, d0, softmin3s(a, b, v0));      // row 2l, col j
        float d1 = t1 - pj;
        float val1 = fmaf(d1, d1, softmin3s(v0, val0, v1));  // row 2l+1, col j
        if (EDGE) {
            bool vj = (unsigned)j < (unsigned)NN;
            val0 = vj ? val0 : BIGK;
            val1 = vj ? val1 : BIGK;
        }
        if (!BOT) {
            // lane63: j = s-63, j%4 == (u+1)%4. collect 4 cols, publish when j%4==3 (u%4==2)
            switch ((u + 1) & 3) {
                case 0: acc.x = val1; break;
                case 1: acc.y = val1; break;
                case 2: acc.z = val1; break;
                case 3: acc.w = val1; break;
            }
            if ((u & 3) == 2) {
                int base = j - 3;
                if (lane == 63 && (!EDGE || (unsigned)base <= (unsigned)(NN - 4))) {
                    bput(bnd_my + base + 0, acc.x);
                    bput(bnd_my + base + 1, acc.y);
                    bput(bnd_my + base + 2, acc.z);
                    bput(bnd_my + base + 3, acc.w);
                }
            }
        } else if (EDGE) {
            if (lane == 63 && s == OUTS) outp[0] = val1 * IK2f;
        }
        v0 = val0; v1 = val1;
        u2 = u1;
        u1 = nbr1(val1, bsel);   // neighbor's v1 @ s, consumed at s+1 (pure VALU)
    }
}

template<bool TOP, bool BOT>
__device__ __forceinline__ void chunk_iter(
    int ci, int lane, bool l0, bool bsel, float t0, float t1,
    float& v0, float& v1, float& u1, float& u2, float& upl,
    float4& acc,
    float* upC, float* upN, float* pcC, float* pcN,
    const float* p_s, const float* __restrict__ bnd_up, float* __restrict__ bnd_my,
    float* __restrict__ outp)
{
    const int cs = SCH * ci;
    const bool fine = (!TOP) && (ci == 0);   // entry chunk: consume at 4-col granularity
    if (!TOP && cs < NN) {
        if (!fine) { if (!uvalid(upC)) upoll(bnd_up + cs, upC); }
        if (cs + SCH < NN) uissue(bnd_up + cs + SCH, upN); // issue for next chunk, no wait
    }
    if (ci + 1 < NCI) pload(p_s, cs + SCH - lane, pcN);

    const bool edge = (ci < 4) || (ci >= 256);
    if (fine)      chunk16<TOP, BOT, true , true >(cs, lane, l0, bsel, t0, t1, v0, v1, u1, u2,
                                                   upl, acc, upC, pcC, bnd_up + cs, bnd_my, outp);
    else if (edge) chunk16<TOP, BOT, true , false>(cs, lane, l0, bsel, t0, t1, v0, v1, u1, u2,
                                                   upl, acc, upC, pcC, nullptr, bnd_my, outp);
    else           chunk16<TOP, BOT, false, false>(cs, lane, l0, bsel, t0, t1, v0, v1, u1, u2,
                                                   upl, acc, upC, pcC, nullptr, bnd_my, outp);
    if (!TOP && cs < NN) upl = upC[SCH - 1];
}

template<bool TOP, bool BOT>
__device__ void stripe(int b, int lane, const float* __restrict__ target,
                       const float* p_s, float* bnd, float* outp)
{
    const float t0 = target[128 * b + 2 * lane]     * SQK2f;
    const float t1 = target[128 * b + 2 * lane + 1] * SQK2f;
    float* bnd_my = bnd + (size_t)b * NN;
    const float* bnd_up = bnd + (size_t)(b - 1) * NN;
    const bool l0 = (lane == 0);
    const bool bsel = (lane != 0) && ((lane & 15) == 0);   // lanes 16/32/48: row-crossing

    float v0 = BIGK, v1 = BIGK, u1 = BIGK, u2 = BIGK, upl = BIGK;
    float4 acc = {BIGK, BIGK, BIGK, BIGK};
    float upA[SCH], upB[SCH];
    float pcA[SCH], pcB[SCH];

    pload(p_s, -lane, pcA);
    // no prologue bulk issue: chunk 0 is consumed via fine 4-col polls

    for (int cp = 0; cp < NCI / 2; ++cp) {
        chunk_iter<TOP, BOT>(2 * cp,     lane, l0, bsel, t0, t1, v0, v1, u1, u2, upl, acc,
                             upA, upB, pcA, pcB, p_s, bnd_up, bnd_my, outp);
        chunk_iter<TOP, BOT>(2 * cp + 1, lane, l0, bsel, t0, t1, v0, v1, u1, u2, upl, acc,
                             upB, upA, pcB, pcA, p_s, bnd_up, bnd_my, outp);
    }
}

__global__ __launch_bounds__(64, 1) void sdtw_pipe19(const float* __restrict__ pred,
                                                     const float* __restrict__ target,
                                                     float* __restrict__ out,
                                                     float* __restrict__ bnd)
{
    __shared__ float p_s[NN];
    const int lane = threadIdx.x;
    const int bid = blockIdx.x;
    const int b = (bid & 7) * 4 + (bid >> 3);   // group stripe-neighbors per XCD
    for (int i = lane; i < NN; i += 64) p_s[i] = pred[i] * SQK2f;
    __syncthreads();
    if (b == 0)                stripe<true , false>(b, lane, target, p_s, bnd, out);
    else if (b == NBLK - 1)    stripe<false, true >(b, lane, target, p_s, bnd, out);
    else                       stripe<false, false>(b, lane, target, p_s, bnd, out);
}

extern "C" void kernel_launch(void* const* d_in, const int* in_sizes, int n_in,
                              void* d_out, int out_size, void* d_ws, size_t ws_size,
                              hipStream_t stream) {
    const float* pred   = (const float*)d_in[0];
    const float* target = (const float*)d_in[1];
    float* out = (float*)d_out;

    const size_t need = (size_t)NBLK * NN * sizeof(float);
    if (ws_size >= need) {
        float* bnd = (float*)d_ws;
        hipMemsetAsync(d_ws, 0xFF, need, stream);   // NaN-sentinel fill (value-carried readiness)
        sdtw_pipe19<<<dim3(NBLK), dim3(64), 0, stream>>>(pred, target, out, bnd);
    } else {
        dilate_sdtw<<<dim3(1), dim3(1024), 0, stream>>>(pred, target, out);
    }
}

// Round 20
// 836.792 us; speedup vs baseline: 2.7013x; 1.1845x over previous
//
#include <hip/hip_runtime.h>

#define NN    4096
#define BIGF  1e8f
// Scaled domain: R' = R * K2, K2 = (1/GAMMA)*log2(e).
// softmin'(a,b,c) = m - log2(1 + exp2(m-med) + exp2(m-max)); loss = R'/K2.
// (the min term's exp2 is exactly 1 and is never computed)
#define SQK2f 12.0112245225638540f    // sqrt(K2)
#define BIGK  1.4426950408889634e10f  // 1e8 * K2
#define IK2f  0.00693147180559945309f // 1/K2 = GAMMA*ln2
#define NBLK  32       // stripes of 128 rows (64 lanes x R=2), skew 63 (r9/r16 mapping)
#define SCH   16       // steps per chunk (r16-validated)
#define NCI   260      // chunks: s = 0..4159
#define OUTS  4158     // lane63: j = 4095 at s = 4095 + 63
#define SENTU 0xFFFFFFFFu   // NaN sentinel: DP values are never NaN

// ---------------- fallback: single-block diagonal kernel (verified r1) ----------------
__global__ __launch_bounds__(1024) void dilate_sdtw(const float* __restrict__ pred,
                                                    const float* __restrict__ target,
                                                    float* __restrict__ out) {
    __shared__ float t_s[NN];
    __shared__ float p_s[NN];
    __shared__ float bufA[NN];
    __shared__ float bufB[NN];
    __shared__ float bufC[NN];
    const int tid = threadIdx.x;
    for (int i = tid; i < NN; i += 1024) {
        t_s[i] = target[i]; p_s[i] = pred[i];
        bufA[i] = BIGF; bufB[i] = BIGF; bufC[i] = BIGF;
    }
    __syncthreads();
    float* r2 = bufA; float* r1 = bufB; float* rn = bufC;
    for (int k = 0; k < 2 * NN - 1; ++k) {
        int ilo = k - (NN - 1); if (ilo < 0) ilo = 0;
        int ihi = (k < NN - 1) ? k : (NN - 1);
        for (int i = ilo + tid; i <= ihi; i += 1024) {
            const int j = k - i;
            float diff = t_s[i] - p_s[j];
            float d = diff * diff;
            float a = (i >= 1 && j >= 1) ? r2[i - 1] : ((k == 0) ? 0.0f : BIGF);
            float b = (i >= 1) ? r1[i - 1] : BIGF;
            float c = (j >= 1) ? r1[i] : BIGF;
            float m = fminf(a, fminf(b, c));
            float s = __expf((m - a) * 100.0f) + __expf((m - b) * 100.0f) + __expf((m - c) * 100.0f);
            rn[i] = d + m - 0.01f * __logf(s);
        }
        __syncthreads();
        float* tmp = r2; r2 = r1; r1 = rn; rn = tmp;
    }
    if (tid == 0) out[0] = r1[NN - 1];
}

// ---- r16 core verbatim; ONLY change: 3-transcendental softmin (min3/med3/max3) ----

__device__ __forceinline__ float softmin3s(float a, float b, float c) {
    float m  = fminf(a, fminf(b, c));                 // -> v_min3_f32
    float md = __builtin_amdgcn_fmed3f(a, b, c);      // v_med3_f32
    float mx = fmaxf(a, fmaxf(b, c));                 // -> v_max3_f32
    float e  = 1.0f + (__builtin_amdgcn_exp2f(m - md) + __builtin_amdgcn_exp2f(m - mx));
    return m - __builtin_amdgcn_logf(e);              // logf builtin = log2
}

// lane l <- lane l-1, whole wave, pure VALU (verified r8-r16):
// row_shr:1 covers lanes 1-15 of each 16-row; row_bcast:15 covers lanes 16/32/48.
__device__ __forceinline__ float nbr1(float v, bool bsel) {
    int iv = __float_as_int(v);
    float a = __int_as_float(__builtin_amdgcn_update_dpp(iv, iv, 0x111, 0xF, 0xF, false)); // row_shr:1
    float b = __int_as_float(__builtin_amdgcn_update_dpp(iv, iv, 0x142, 0xF, 0xF, false)); // row_bcast:15
    return bsel ? b : a;
}

__device__ __forceinline__ void bput(float* p, float v) {
    __hip_atomic_store((unsigned int*)p, __float_as_uint(v),
                       __ATOMIC_RELAXED, __HIP_MEMORY_SCOPE_AGENT);
}
__device__ __forceinline__ unsigned int bgetu(const float* p) {
    return __hip_atomic_load((const unsigned int*)p,
                             __ATOMIC_RELAXED, __HIP_MEMORY_SCOPE_AGENT);
}

// issue SCH relaxed loads into regs; no use -> wait deferred to uvalid
__device__ __forceinline__ void uissue(const float* src, float* dst) {
#pragma unroll
    for (int q = 0; q < SCH; ++q) dst[q] = __uint_as_float(bgetu(src + q));
}
__device__ __forceinline__ bool uvalid(const float* dst) {
    bool ok = true;
#pragma unroll
    for (int q = 0; q < SCH; ++q) ok &= (__float_as_uint(dst[q]) != SENTU);
    return ok;
}
__device__ __forceinline__ void upoll(const float* src, float* dst) {
    for (;;) {
        uissue(src, dst);
        if (uvalid(dst)) return;
        __builtin_amdgcn_s_sleep(1);
    }
}

// p for one chunk: SCH columns from per-lane base (clamped), scalar LDS reads
__device__ __forceinline__ void pload(const float* p_s, int base, float* dst) {
#pragma unroll
    for (int q = 0; q < SCH; ++q) {
        int idx = base + q;
        idx = idx < 0 ? 0 : (idx > NN - 1 ? NN - 1 : idx);
        dst[q] = p_s[idx];
    }
}

template<bool TOP, bool BOT, bool EDGE>
__device__ __forceinline__ void chunk16(
    int cs, int lane, bool l0, bool bsel, float t0, float t1,
    float& v0, float& v1, float& u1, float& u2, float upl,
    float4& acc, const float* upc, const float* pc,
    float* __restrict__ bnd_my, float* __restrict__ outp)
{
#pragma unroll
    for (int u = 0; u < SCH; ++u) {
        const int s = cs + u;
        const int j = s - lane;          // off(l) = l, skew 63
        float a, b;
        if (TOP) {
            a = l0 ? ((s == 0) ? 0.0f : BIGK) : u2;
            b = l0 ? BIGK : u1;
        } else {
            float upj  = upc[u];
            float upjm = (u == 0) ? upl : upc[u - 1];
            a = l0 ? upjm : u2;
            b = l0 ? upj  : u1;
        }
        float pj = pc[u];
        float d0 = t0 - pj;
        float val0 = fmaf(d0, d0, softmin3s(a, b, v0));      // row 2l, col j
        float d1 = t1 - pj;
        float val1 = fmaf(d1, d1, softmin3s(v0, val0, v1));  // row 2l+1, col j
        if (EDGE) {
            bool vj = (unsigned)j < (unsigned)NN;
            val0 = vj ? val0 : BIGK;
            val1 = vj ? val1 : BIGK;
        }
        if (!BOT) {
            // lane63: j = s-63, j%4 == (u+1)%4. collect 4 cols, publish when j%4==3 (u%4==2)
            switch ((u + 1) & 3) {
                case 0: acc.x = val1; break;
                case 1: acc.y = val1; break;
                case 2: acc.z = val1; break;
                case 3: acc.w = val1; break;
            }
            if ((u & 3) == 2) {
                int base = j - 3;
                if (lane == 63 && (!EDGE || (unsigned)base <= (unsigned)(NN - 4))) {
                    bput(bnd_my + base + 0, acc.x);
                    bput(bnd_my + base + 1, acc.y);
                    bput(bnd_my + base + 2, acc.z);
                    bput(bnd_my + base + 3, acc.w);
                }
            }
        } else if (EDGE) {
            if (lane == 63 && s == OUTS) outp[0] = val1 * IK2f;
        }
        v0 = val0; v1 = val1;
        u2 = u1;
        u1 = nbr1(val1, bsel);   // neighbor's v1 @ s, consumed at s+1 (pure VALU)
    }
}

template<bool TOP, bool BOT>
__device__ __forceinline__ void chunk_iter(
    int ci, int lane, bool l0, bool bsel, float t0, float t1,
    float& v0, float& v1, float& u1, float& u2, float& upl,
    float4& acc,
    float* upC, float* upN, float* pcC, float* pcN,
    const float* p_s, const float* __restrict__ bnd_up, float* __restrict__ bnd_my,
    float* __restrict__ outp)
{
    const int cs = SCH * ci;
    if (!TOP && cs < NN) {
        if (!uvalid(upC)) upoll(bnd_up + cs, upC);        // fast path: issued last chunk
        if (cs + SCH < NN) uissue(bnd_up + cs + SCH, upN); // issue for next chunk, no wait
    }
    if (ci + 1 < NCI) pload(p_s, cs + SCH - lane, pcN);

    const bool edge = (ci < 4) || (ci >= 256);
    if (edge) chunk16<TOP, BOT, true >(cs, lane, l0, bsel, t0, t1, v0, v1, u1, u2,
                                       upl, acc, upC, pcC, bnd_my, outp);
    else      chunk16<TOP, BOT, false>(cs, lane, l0, bsel, t0, t1, v0, v1, u1, u2,
                                       upl, acc, upC, pcC, bnd_my, outp);
    if (!TOP) upl = upC[SCH - 1];
}

template<bool TOP, bool BOT>
__device__ void stripe(int b, int lane, const float* __restrict__ target,
                       const float* p_s, float* bnd, float* outp)
{
    const float t0 = target[128 * b + 2 * lane]     * SQK2f;
    const float t1 = target[128 * b + 2 * lane + 1] * SQK2f;
    float* bnd_my = bnd + (size_t)b * NN;
    const float* bnd_up = bnd + (size_t)(b - 1) * NN;
    const bool l0 = (lane == 0);
    const bool bsel = (lane != 0) && ((lane & 15) == 0);   // lanes 16/32/48: row-crossing

    float v0 = BIGK, v1 = BIGK, u1 = BIGK, u2 = BIGK, upl = BIGK;
    float4 acc = {BIGK, BIGK, BIGK, BIGK};
    float upA[SCH], upB[SCH];
    float pcA[SCH], pcB[SCH];

    pload(p_s, -lane, pcA);
    if (!TOP) uissue(bnd_up, upA);   // prologue issue for chunk 0

    for (int cp = 0; cp < NCI / 2; ++cp) {
        chunk_iter<TOP, BOT>(2 * cp,     lane, l0, bsel, t0, t1, v0, v1, u1, u2, upl, acc,
                             upA, upB, pcA, pcB, p_s, bnd_up, bnd_my, outp);
        chunk_iter<TOP, BOT>(2 * cp + 1, lane, l0, bsel, t0, t1, v0, v1, u1, u2, upl, acc,
                             upB, upA, pcB, pcA, p_s, bnd_up, bnd_my, outp);
    }
}

__global__ __launch_bounds__(64, 1) void sdtw_pipe20(const float* __restrict__ pred,
                                                     const float* __restrict__ target,
                                                     float* __restrict__ out,
                                                     float* __restrict__ bnd)
{
    __shared__ float p_s[NN];
    const int lane = threadIdx.x;
    const int bid = blockIdx.x;
    const int b = (bid & 7) * 4 + (bid >> 3);   // group stripe-neighbors per XCD
    for (int i = lane; i < NN; i += 64) p_s[i] = pred[i] * SQK2f;
    __syncthreads();
    if (b == 0)                stripe<true , false>(b, lane, target, p_s, bnd, out);
    else if (b == NBLK - 1)    stripe<false, true >(b, lane, target, p_s, bnd, out);
    else                       stripe<false, false>(b, lane, target, p_s, bnd, out);
}

extern "C" void kernel_launch(void* const* d_in, const int* in_sizes, int n_in,
                              void* d_out, int out_size, void* d_ws, size_t ws_size,
                              hipStream_t stream) {
    const float* pred   = (const float*)d_in[0];
    const float* target = (const float*)d_in[1];
    float* out = (float*)d_out;

    const size_t need = (size_t)NBLK * NN * sizeof(float);
    if (ws_size >= need) {
        float* bnd = (float*)d_ws;
        hipMemsetAsync(d_ws, 0xFF, need, stream);   // NaN-sentinel fill (value-carried readiness)
        sdtw_pipe20<<<dim3(NBLK), dim3(64), 0, stream>>>(pred, target, out, bnd);
    } else {
        dilate_sdtw<<<dim3(1), dim3(1024), 0, stream>>>(pred, target, out);
    }
}